// Round 1
// baseline (475.611 us; speedup 1.0000x reference)
//
#include <hip/hip_runtime.h>
#include <math.h>

#define EPSN 1e-4f
#define SEQ 2304
// qkv buffer layout: [(n*8+h)*3 + which][d(32)][s(2304)]  (73728 floats per (nh,which))

// ---------------- Kernel 1: weight normalization ----------------
// w_eff[o,i] = w[o,i] / ((EPS + ||w[o]||/16) * 16) = w[o,i] / (16*EPS + ||w[o]||)
__global__ __launch_bounds__(256) void wnorm_kernel(const float* __restrict__ w_qkv,
                                                    const float* __restrict__ w_out,
                                                    float* __restrict__ wq_eff,
                                                    float* __restrict__ wo_eff) {
    int row = blockIdx.x;
    const float* src;
    float* dst;
    if (row < 768) { src = w_qkv + row * 256; dst = wq_eff + row * 256; }
    else           { src = w_out + (row - 768) * 256; dst = wo_eff + (row - 768) * 256; }
    float v = src[threadIdx.x];
    float ss = v * v;
    for (int off = 32; off > 0; off >>= 1) ss += __shfl_down(ss, off, 64);
    __shared__ float red[4];
    __shared__ float scale_s;
    int lane = threadIdx.x & 63, wid = threadIdx.x >> 6;
    if (lane == 0) red[wid] = ss;
    __syncthreads();
    if (threadIdx.x == 0) {
        float t = red[0] + red[1] + red[2] + red[3];
        scale_s = 1.0f / (sqrtf(t) + 16.0f * EPSN);
    }
    __syncthreads();
    dst[threadIdx.x] = v * scale_s;
}

// ---------------- Kernel 2: QKV 1x1 conv (GEMM 768x256 @ 256xSEQ per n) ----------------
// out channel o -> h = o/96, d = (o%96)/3, which = o%3 ; dst layout [nh*3+which][d][s]
__global__ __launch_bounds__(256) void qkv_conv_kernel(const float* __restrict__ x,
                                                       const float* __restrict__ w,
                                                       float* __restrict__ qkv) {
    int ot = blockIdx.x;   // 0..11 (64 out ch each)
    int st = blockIdx.y;   // 0..35 (64 s each)
    int n  = blockIdx.z;   // 0..1
    __shared__ float Ws[16][68];
    __shared__ float Xs[16][68];
    int tid = threadIdx.x;
    int ty = tid >> 4, tx = tid & 15;
    float acc[4][4] = {};
    const float* xb = x + (size_t)n * 256 * SEQ + st * 64;
    for (int kc = 0; kc < 16; ++kc) {
        __syncthreads();
#pragma unroll
        for (int p = 0; p < 4; ++p) {
            int e = tid + p * 256;
            int oo = e >> 4, ii = e & 15;
            Ws[ii][oo] = w[(ot * 64 + oo) * 256 + kc * 16 + ii];
            int ss2 = e & 63, i2 = e >> 6;
            Xs[i2][ss2] = xb[(size_t)(kc * 16 + i2) * SEQ + ss2];
        }
        __syncthreads();
#pragma unroll
        for (int ii = 0; ii < 16; ++ii) {
            float4 a4 = *(const float4*)&Ws[ii][ty * 4];
            float4 b4 = *(const float4*)&Xs[ii][tx * 4];
            float av[4] = {a4.x, a4.y, a4.z, a4.w};
            float bv[4] = {b4.x, b4.y, b4.z, b4.w};
#pragma unroll
            for (int i = 0; i < 4; ++i)
#pragma unroll
                for (int j = 0; j < 4; ++j) acc[i][j] += av[i] * bv[j];
        }
    }
#pragma unroll
    for (int i = 0; i < 4; ++i) {
        int o = ot * 64 + ty * 4 + i;
        int h = o / 96, r = o % 96;
        int d = r / 3, wh = r % 3;
        float* dst = qkv + ((size_t)((n * 8 + h) * 3 + wh) * 32 + d) * SEQ + st * 64 + tx * 4;
        *(float4*)dst = make_float4(acc[i][0], acc[i][1], acc[i][2], acc[i][3]);
    }
}

// ---------------- Kernel 3: normalize over head-dim (32) ----------------
__global__ __launch_bounds__(256) void dnorm_kernel(float* __restrict__ qkv) {
    int g = blockIdx.x;                       // 0..47 = (nh*3+which)
    int s = blockIdx.y * 256 + threadIdx.x;   // 0..2303
    float* base = qkv + (size_t)g * 73728 + s;
    float v[32];
    float ss = 0.f;
#pragma unroll
    for (int d = 0; d < 32; ++d) { v[d] = base[(size_t)d * SEQ]; ss += v[d] * v[d]; }
    float inv = 1.0f / (EPSN + sqrtf(ss * (1.0f / 32.0f)));
#pragma unroll
    for (int d = 0; d < 32; ++d) base[(size_t)d * SEQ] = v[d] * inv;
}

// ---------------- Kernel 4: flash attention ----------------
// grid: (36 q-tiles, 16 nh); block 256
__global__ __launch_bounds__(256) void attn_kernel(const float* __restrict__ qkv,
                                                   float* __restrict__ y2) {
    int qt = blockIdx.x;
    int nh = blockIdx.y;
    const float* Qg = qkv + (size_t)(nh * 3 + 0) * 73728;
    const float* Kg = qkv + (size_t)(nh * 3 + 1) * 73728;
    const float* Vg = qkv + (size_t)(nh * 3 + 2) * 73728;
    __shared__ float Qs[32][68];
    __shared__ float Ks[32][68];
    __shared__ float Vs[32][65];
    __shared__ float P[64][68];
    __shared__ float RM[16][65];
    __shared__ float RS[16][65];
    __shared__ float mS[64], lS[64], aS[64];
    int tid = threadIdx.x;
    int ty = tid >> 4, tx = tid & 15;
    int cg = tid >> 4, qg = tid & 15;   // O mapping: c = cg*2+m, q = qg*4+i
    float o[2][4] = {};
    const float scale = 0.17677669529663687f; // 1/sqrt(32)
#pragma unroll
    for (int p = 0; p < 8; ++p) {
        int e = tid + p * 256;
        int qq = e & 63, d = e >> 6;
        Qs[d][qq] = Qg[(size_t)d * SEQ + qt * 64 + qq] * scale;
    }
    if (tid < 64) { mS[tid] = -1e30f; lS[tid] = 0.f; }
    __syncthreads();

    for (int kt = 0; kt < 36; ++kt) {
        int k0 = kt * 64;
#pragma unroll
        for (int p = 0; p < 8; ++p) {
            int e = tid + p * 256;
            int j = e & 63, d = e >> 6;
            Ks[d][j] = Kg[(size_t)d * SEQ + k0 + j];
            Vs[d][j] = Vg[(size_t)d * SEQ + k0 + j];
        }
        __syncthreads();
        // S = Q^T K  (4x4 per thread)
        float sacc[4][4] = {};
#pragma unroll
        for (int d = 0; d < 32; ++d) {
            float4 a4 = *(const float4*)&Qs[d][ty * 4];
            float4 b4 = *(const float4*)&Ks[d][tx * 4];
            float av[4] = {a4.x, a4.y, a4.z, a4.w};
            float bv[4] = {b4.x, b4.y, b4.z, b4.w};
#pragma unroll
            for (int i = 0; i < 4; ++i)
#pragma unroll
                for (int j = 0; j < 4; ++j) sacc[i][j] += av[i] * bv[j];
        }
        // per-thread row-max partials
#pragma unroll
        for (int i = 0; i < 4; ++i) {
            float mx = fmaxf(fmaxf(sacc[i][0], sacc[i][1]), fmaxf(sacc[i][2], sacc[i][3]));
            RM[tx][ty * 4 + i] = mx;
        }
        __syncthreads();
        if (tid < 64) {
            float mo = mS[tid];
            float mx = RM[0][tid];
#pragma unroll
            for (int p2 = 1; p2 < 16; ++p2) mx = fmaxf(mx, RM[p2][tid]);
            float mn = fmaxf(mo, mx);
            mS[tid] = mn;
            aS[tid] = __expf(mo - mn);
        }
        __syncthreads();
        // exp + P write + row-sum partials ; O rescale
#pragma unroll
        for (int i = 0; i < 4; ++i) {
            int row = ty * 4 + i;
            float mrow = mS[row];
            float rs = 0.f;
#pragma unroll
            for (int j = 0; j < 4; ++j) {
                float e = __expf(sacc[i][j] - mrow);
                P[row][tx * 4 + j] = e;
                rs += e;
            }
            RS[tx][row] = rs;
        }
        {
            float al[4];
#pragma unroll
            for (int i2 = 0; i2 < 4; ++i2) al[i2] = aS[qg * 4 + i2];
#pragma unroll
            for (int m2 = 0; m2 < 2; ++m2)
#pragma unroll
                for (int i2 = 0; i2 < 4; ++i2) o[m2][i2] *= al[i2];
        }
        __syncthreads();
        if (tid < 64) {
            float rs = RS[0][tid];
#pragma unroll
            for (int p2 = 1; p2 < 16; ++p2) rs += RS[p2][tid];
            lS[tid] = lS[tid] * aS[tid] + rs;
        }
        // O += P * V^T   (thread: c in {cg*2, cg*2+1}, q in {qg*4..qg*4+3})
        int c0 = cg * 2;
#pragma unroll 4
        for (int j = 0; j < 64; ++j) {
            float v0 = Vs[c0][j], v1 = Vs[c0 + 1][j];
            float pj[4];
#pragma unroll
            for (int i = 0; i < 4; ++i) pj[i] = P[qg * 4 + i][j];
#pragma unroll
            for (int i = 0; i < 4; ++i) { o[0][i] += pj[i] * v0; o[1][i] += pj[i] * v1; }
        }
        __syncthreads();
    }
    // epilogue: divide by l, write y2[n][h*32+c][s]
    int n = nh >> 3, h = nh & 7;
#pragma unroll
    for (int m2 = 0; m2 < 2; ++m2) {
        int c = cg * 2 + m2;
        float* dst = y2 + ((size_t)(n * 256) + h * 32 + c) * SEQ + qt * 64 + qg * 4;
#pragma unroll
        for (int i2 = 0; i2 < 4; ++i2) dst[i2] = o[m2][i2] / lS[qg * 4 + i2];
    }
}

// ---------------- Kernel 5: out 1x1 conv + residual mix ----------------
__global__ __launch_bounds__(256) void out_conv_kernel(const float* __restrict__ y2,
                                                       const float* __restrict__ w,
                                                       const float* __restrict__ x,
                                                       float* __restrict__ out) {
    int ot = blockIdx.x;   // 0..3
    int st = blockIdx.y;   // 0..35
    int n  = blockIdx.z;   // 0..1
    __shared__ float Ws[16][68];
    __shared__ float Xs[16][68];
    int tid = threadIdx.x;
    int ty = tid >> 4, tx = tid & 15;
    float acc[4][4] = {};
    const float* yb = y2 + (size_t)n * 256 * SEQ + st * 64;
    for (int kc = 0; kc < 16; ++kc) {
        __syncthreads();
#pragma unroll
        for (int p = 0; p < 4; ++p) {
            int e = tid + p * 256;
            int oo = e >> 4, ii = e & 15;
            Ws[ii][oo] = w[(ot * 64 + oo) * 256 + kc * 16 + ii];
            int ss2 = e & 63, i2 = e >> 6;
            Xs[i2][ss2] = yb[(size_t)(kc * 16 + i2) * SEQ + ss2];
        }
        __syncthreads();
#pragma unroll
        for (int ii = 0; ii < 16; ++ii) {
            float4 a4 = *(const float4*)&Ws[ii][ty * 4];
            float4 b4 = *(const float4*)&Xs[ii][tx * 4];
            float av[4] = {a4.x, a4.y, a4.z, a4.w};
            float bv[4] = {b4.x, b4.y, b4.z, b4.w};
#pragma unroll
            for (int i = 0; i < 4; ++i)
#pragma unroll
                for (int j = 0; j < 4; ++j) acc[i][j] += av[i] * bv[j];
        }
    }
    const float k0 = 0.7f * 1.3130643285972254f;   // (1-t)/sqrt((1-t)^2+t^2)
    const float k1 = 0.3f * 1.3130643285972254f;   // t/sqrt(...)
#pragma unroll
    for (int i = 0; i < 4; ++i) {
        int o = ot * 64 + ty * 4 + i;
        size_t idx = ((size_t)(n * 256) + o) * SEQ + st * 64 + tx * 4;
        float4 xv = *(const float4*)&x[idx];
        float4 r;
        r.x = k0 * xv.x + k1 * acc[i][0];
        r.y = k0 * xv.y + k1 * acc[i][1];
        r.z = k0 * xv.z + k1 * acc[i][2];
        r.w = k0 * xv.w + k1 * acc[i][3];
        *(float4*)&out[idx] = r;
    }
}

extern "C" void kernel_launch(void* const* d_in, const int* in_sizes, int n_in,
                              void* d_out, int out_size, void* d_ws, size_t ws_size,
                              hipStream_t stream) {
    (void)in_sizes; (void)n_in; (void)out_size; (void)ws_size;
    const float* x     = (const float*)d_in[0];
    const float* w_qkv = (const float*)d_in[1];
    const float* w_out = (const float*)d_in[2];
    float* out = (float*)d_out;
    float* ws  = (float*)d_ws;
    float* wq_eff = ws;              // 768*256   = 196608 floats
    float* wo_eff = ws + 196608;     // 256*256   =  65536 floats
    float* qkv    = ws + 262144;     // 2*768*2304 = 3538944 floats
    float* y2     = ws + 3801088;    // 2*256*2304 = 1179648 floats

    hipLaunchKernelGGL(wnorm_kernel, dim3(1024), dim3(256), 0, stream,
                       w_qkv, w_out, wq_eff, wo_eff);
    hipLaunchKernelGGL(qkv_conv_kernel, dim3(12, 36, 2), dim3(256), 0, stream,
                       x, wq_eff, qkv);
    hipLaunchKernelGGL(dnorm_kernel, dim3(48, 9), dim3(256), 0, stream, qkv);
    hipLaunchKernelGGL(attn_kernel, dim3(36, 16), dim3(256), 0, stream, qkv, y2);
    hipLaunchKernelGGL(out_conv_kernel, dim3(4, 36, 2), dim3(256), 0, stream,
                       y2, wo_eff, x, out);
}

// Round 2
// 174.055 us; speedup vs baseline: 2.7325x; 2.7325x over previous
//
#include <hip/hip_runtime.h>
#include <math.h>

#define EPSN 1e-4f
#define SEQ 2304

using bf16x8 = __attribute__((ext_vector_type(8))) short;
using f32x4  = __attribute__((ext_vector_type(4))) float;

__device__ inline unsigned short f2bf(float x) {
    union { float f; unsigned u; } c; c.f = x;
    unsigned u = c.u;
    u += 0x7fffu + ((u >> 16) & 1u);
    return (unsigned short)(u >> 16);
}
__device__ inline float bf2f(unsigned short b) {
    union { unsigned u; float f; } c; c.u = ((unsigned)b) << 16;
    return c.f;
}

// ---------------- Kernel 1: weight normalization ----------------
// w_eff[o,i] = w[o,i] / (16*EPS + ||w[o]||)
__global__ __launch_bounds__(256) void wnorm_kernel(const float* __restrict__ w_qkv,
                                                    const float* __restrict__ w_out,
                                                    float* __restrict__ wq_eff,
                                                    float* __restrict__ wo_eff) {
    int row = blockIdx.x;
    const float* src;
    float* dst;
    if (row < 768) { src = w_qkv + row * 256; dst = wq_eff + row * 256; }
    else           { src = w_out + (row - 768) * 256; dst = wo_eff + (row - 768) * 256; }
    float v = src[threadIdx.x];
    float ss = v * v;
    for (int off = 32; off > 0; off >>= 1) ss += __shfl_down(ss, off, 64);
    __shared__ float red[4];
    __shared__ float scale_s;
    int lane = threadIdx.x & 63, wid = threadIdx.x >> 6;
    if (lane == 0) red[wid] = ss;
    __syncthreads();
    if (threadIdx.x == 0) {
        float t = red[0] + red[1] + red[2] + red[3];
        scale_s = 1.0f / (sqrtf(t) + 16.0f * EPSN);
    }
    __syncthreads();
    dst[threadIdx.x] = v * scale_s;
}

// ---------------- Kernel 2: QKV 1x1 conv, bf16 output ----------------
// out channel o -> h = o/96, d = (o%96)/3, which = o%3 ; dst layout [nh*3+which][d][s] (bf16)
__global__ __launch_bounds__(256) void qkv_conv_kernel(const float* __restrict__ x,
                                                       const float* __restrict__ w,
                                                       unsigned short* __restrict__ qkvb) {
    int ot = blockIdx.x;   // 0..11
    int st = blockIdx.y;   // 0..35
    int n  = blockIdx.z;   // 0..1
    __shared__ float Ws[16][68];
    __shared__ float Xs[16][68];
    int tid = threadIdx.x;
    int ty = tid >> 4, tx = tid & 15;
    float acc[4][4] = {};
    const float* xb = x + (size_t)n * 256 * SEQ + st * 64;
    for (int kc = 0; kc < 16; ++kc) {
        __syncthreads();
#pragma unroll
        for (int p = 0; p < 4; ++p) {
            int e = tid + p * 256;
            int oo = e >> 4, ii = e & 15;
            Ws[ii][oo] = w[(ot * 64 + oo) * 256 + kc * 16 + ii];
            int ss2 = e & 63, i2 = e >> 6;
            Xs[i2][ss2] = xb[(size_t)(kc * 16 + i2) * SEQ + ss2];
        }
        __syncthreads();
#pragma unroll
        for (int ii = 0; ii < 16; ++ii) {
            float4 a4 = *(const float4*)&Ws[ii][ty * 4];
            float4 b4 = *(const float4*)&Xs[ii][tx * 4];
            float av[4] = {a4.x, a4.y, a4.z, a4.w};
            float bv[4] = {b4.x, b4.y, b4.z, b4.w};
#pragma unroll
            for (int i = 0; i < 4; ++i)
#pragma unroll
                for (int j = 0; j < 4; ++j) acc[i][j] += av[i] * bv[j];
        }
    }
#pragma unroll
    for (int i = 0; i < 4; ++i) {
        int o = ot * 64 + ty * 4 + i;
        int h = o / 96, r = o % 96;
        int d = r / 3, wh = r % 3;
        unsigned short* dst = qkvb + ((size_t)((n * 8 + h) * 3 + wh) * 32 + d) * SEQ + st * 64 + tx * 4;
        uint2 pk;
        pk.x = (unsigned)f2bf(acc[i][0]) | ((unsigned)f2bf(acc[i][1]) << 16);
        pk.y = (unsigned)f2bf(acc[i][2]) | ((unsigned)f2bf(acc[i][3]) << 16);
        *(uint2*)dst = pk;
    }
}

// ---------------- Kernel 3: d-normalize, emit MFMA-friendly bf16 layouts ----------------
// qn, kn: [nh][s][d]  (d contiguous, 32 per row);  vn: [nh][d][s]
// Q gets 1/sqrt(32) softmax scale folded in.
__global__ __launch_bounds__(256) void dnorm_bf16_kernel(const unsigned short* __restrict__ qkvb,
                                                         unsigned short* __restrict__ qn,
                                                         unsigned short* __restrict__ kn,
                                                         unsigned short* __restrict__ vn) {
    int nh = blockIdx.x;                      // 0..15
    int s = blockIdx.y * 256 + threadIdx.x;   // 0..2303
    const float qscale = 0.17677669529663687f; // 1/sqrt(32)
#pragma unroll
    for (int which = 0; which < 3; ++which) {
        const unsigned short* base = qkvb + ((size_t)(nh * 3 + which) * 32) * SEQ + s;
        float v[32];
        float ss = 0.f;
#pragma unroll
        for (int d = 0; d < 32; ++d) { v[d] = bf2f(base[(size_t)d * SEQ]); ss += v[d] * v[d]; }
        float inv = 1.0f / (EPSN + sqrtf(ss * (1.0f / 32.0f)));
        if (which == 0) inv *= qscale;
        if (which == 2) {
            unsigned short* dst = vn + (size_t)nh * 73728 + s;
#pragma unroll
            for (int d = 0; d < 32; ++d) dst[(size_t)d * SEQ] = f2bf(v[d] * inv);
        } else {
            unsigned short* dst = (which ? kn : qn) + (size_t)nh * 73728 + (size_t)s * 32;
            unsigned wbuf[16];
#pragma unroll
            for (int j = 0; j < 16; ++j)
                wbuf[j] = (unsigned)f2bf(v[2 * j] * inv) | ((unsigned)f2bf(v[2 * j + 1] * inv) << 16);
#pragma unroll
            for (int j = 0; j < 4; ++j) {
                uint4 t = make_uint4(wbuf[4 * j], wbuf[4 * j + 1], wbuf[4 * j + 2], wbuf[4 * j + 3]);
                *(uint4*)(dst + j * 8) = t;
            }
        }
    }
}

// ---------------- Kernel 4: MFMA flash attention ----------------
// grid (36 q-tiles, 16 nh), block 256 = 4 waves; each wave owns 16 q rows.
// No online max: |S| <= sqrt(32) after scaling -> exp safe in fp32.
__global__ __launch_bounds__(256) void attn_mfma_kernel(const unsigned short* __restrict__ qn,
                                                        const unsigned short* __restrict__ kn,
                                                        const unsigned short* __restrict__ vn,
                                                        float* __restrict__ y2) {
    __shared__ __align__(16) unsigned short Ks[64][40];     // [key][d], pad 40
    __shared__ __align__(16) unsigned short Vs[32][72];     // [c][key], pad 72
    __shared__ __align__(16) unsigned short Ps[4][16][72];  // per-wave [q][key]
    int tid = threadIdx.x;
    int wave = tid >> 6, lane = tid & 63;
    int ln = lane & 15, quad = lane >> 4;
    int qt = blockIdx.x, nh = blockIdx.y;
    const unsigned short* Qg = qn + (size_t)nh * 73728;
    const unsigned short* Kg = kn + (size_t)nh * 73728;
    const unsigned short* Vg = vn + (size_t)nh * 73728;

    // Q A-fragment: A[m=ln][k=quad*8+j], rows q0+ln, held for whole kernel
    bf16x8 qf = *(const bf16x8*)(Qg + (size_t)(qt * 64 + wave * 16 + ln) * 32 + quad * 8);
    bf16x8 ones;
#pragma unroll
    for (int i = 0; i < 8; ++i) ones[i] = (short)0x3F80;  // bf16 1.0

    f32x4 o0 = {0.f, 0.f, 0.f, 0.f};
    f32x4 o1 = {0.f, 0.f, 0.f, 0.f};
    f32x4 lac = {0.f, 0.f, 0.f, 0.f};

    for (int kt = 0; kt < 36; ++kt) {
        int k0 = kt * 64;
        __syncthreads();  // previous tile's frag reads done before overwrite
        {   // stage K tile: 64 rows x 32 d, contiguous 4KB in global
            uint4 t = *(const uint4*)(Kg + (size_t)k0 * 32 + tid * 8);
            *(uint4*)(&Ks[tid >> 2][(tid & 3) * 8]) = t;
        }
        {   // stage V tile: 32 rows x 64 keys
            uint4 t = *(const uint4*)(Vg + (size_t)(tid >> 3) * SEQ + k0 + (tid & 7) * 8);
            *(uint4*)(&Vs[tid >> 3][(tid & 7) * 8]) = t;
        }
        __syncthreads();

        const f32x4 zero = {0.f, 0.f, 0.f, 0.f};
#pragma unroll
        for (int c = 0; c < 4; ++c) {
            // K B-fragment: B[k=quad*8+j][n=ln], keys c*16+ln
            bf16x8 kf = *(const bf16x8*)(&Ks[c * 16 + ln][quad * 8]);
            f32x4 sc = __builtin_amdgcn_mfma_f32_16x16x32_bf16(qf, kf, zero, 0, 0, 0);
            // C layout: col(key)=ln, row(q)=quad*4+r -> P[q][key]
#pragma unroll
            for (int r = 0; r < 4; ++r)
                Ps[wave][quad * 4 + r][c * 16 + ln] = f2bf(__expf(sc[r]));
        }
        __syncthreads();  // conservative: ensure P visible before A-frag reads

#pragma unroll
        for (int kc = 0; kc < 2; ++kc) {
            bf16x8 pf = *(const bf16x8*)(&Ps[wave][ln][kc * 32 + quad * 8]);
            bf16x8 v0 = *(const bf16x8*)(&Vs[ln][kc * 32 + quad * 8]);
            bf16x8 v1 = *(const bf16x8*)(&Vs[16 + ln][kc * 32 + quad * 8]);
            lac = __builtin_amdgcn_mfma_f32_16x16x32_bf16(pf, ones, lac, 0, 0, 0);  // row sums
            o0  = __builtin_amdgcn_mfma_f32_16x16x32_bf16(pf, v0, o0, 0, 0, 0);
            o1  = __builtin_amdgcn_mfma_f32_16x16x32_bf16(pf, v1, o1, 0, 0, 0);
        }
    }

    // epilogue: O rows q=quad*4+r, cols c=ln / 16+ln ; y2[n][h*32+c][s]
    int n = nh >> 3, h = nh & 7;
#pragma unroll
    for (int r = 0; r < 4; ++r) {
        float inv = 1.0f / lac[r];
        int q = qt * 64 + wave * 16 + quad * 4 + r;
        y2[((size_t)(n * 256) + h * 32 + ln) * SEQ + q]      = o0[r] * inv;
        y2[((size_t)(n * 256) + h * 32 + 16 + ln) * SEQ + q] = o1[r] * inv;
    }
}

// ---------------- Kernel 5: out 1x1 conv + residual mix ----------------
__global__ __launch_bounds__(256) void out_conv_kernel(const float* __restrict__ y2,
                                                       const float* __restrict__ w,
                                                       const float* __restrict__ x,
                                                       float* __restrict__ out) {
    int ot = blockIdx.x;   // 0..3
    int st = blockIdx.y;   // 0..35
    int n  = blockIdx.z;   // 0..1
    __shared__ float Ws[16][68];
    __shared__ float Xs[16][68];
    int tid = threadIdx.x;
    int ty = tid >> 4, tx = tid & 15;
    float acc[4][4] = {};
    const float* yb = y2 + (size_t)n * 256 * SEQ + st * 64;
    for (int kc = 0; kc < 16; ++kc) {
        __syncthreads();
#pragma unroll
        for (int p = 0; p < 4; ++p) {
            int e = tid + p * 256;
            int oo = e >> 4, ii = e & 15;
            Ws[ii][oo] = w[(ot * 64 + oo) * 256 + kc * 16 + ii];
            int ss2 = e & 63, i2 = e >> 6;
            Xs[i2][ss2] = yb[(size_t)(kc * 16 + i2) * SEQ + ss2];
        }
        __syncthreads();
#pragma unroll
        for (int ii = 0; ii < 16; ++ii) {
            float4 a4 = *(const float4*)&Ws[ii][ty * 4];
            float4 b4 = *(const float4*)&Xs[ii][tx * 4];
            float av[4] = {a4.x, a4.y, a4.z, a4.w};
            float bv[4] = {b4.x, b4.y, b4.z, b4.w};
#pragma unroll
            for (int i = 0; i < 4; ++i)
#pragma unroll
                for (int j = 0; j < 4; ++j) acc[i][j] += av[i] * bv[j];
        }
    }
    const float k0 = 0.7f * 1.3130643285972254f;   // (1-t)/sqrt((1-t)^2+t^2)
    const float k1 = 0.3f * 1.3130643285972254f;   // t/sqrt(...)
#pragma unroll
    for (int i = 0; i < 4; ++i) {
        int o = ot * 64 + ty * 4 + i;
        size_t idx = ((size_t)(n * 256) + o) * SEQ + st * 64 + tx * 4;
        float4 xv = *(const float4*)&x[idx];
        float4 r;
        r.x = k0 * xv.x + k1 * acc[i][0];
        r.y = k0 * xv.y + k1 * acc[i][1];
        r.z = k0 * xv.z + k1 * acc[i][2];
        r.w = k0 * xv.w + k1 * acc[i][3];
        *(float4*)&out[idx] = r;
    }
}

extern "C" void kernel_launch(void* const* d_in, const int* in_sizes, int n_in,
                              void* d_out, int out_size, void* d_ws, size_t ws_size,
                              hipStream_t stream) {
    (void)in_sizes; (void)n_in; (void)out_size; (void)ws_size;
    const float* x     = (const float*)d_in[0];
    const float* w_qkv = (const float*)d_in[1];
    const float* w_out = (const float*)d_in[2];
    float* out = (float*)d_out;
    float* ws  = (float*)d_ws;
    // layout (float offsets), total 19.92 MB (same footprint as round 1):
    float* wq_eff = ws;                                     // 196608 f
    float* wo_eff = ws + 196608;                            // 65536 f
    unsigned short* qkvb = (unsigned short*)(ws + 262144);  // 3538944 shorts (1769472 f)
    unsigned short* qn   = (unsigned short*)(ws + 2031616); // 1179648 shorts
    unsigned short* kn   = (unsigned short*)(ws + 2621440); // 1179648 shorts
    unsigned short* vn   = (unsigned short*)(ws + 3211264); // 1179648 shorts
    float* y2 = ws + 3801088;                               // 1179648 f

    hipLaunchKernelGGL(wnorm_kernel, dim3(1024), dim3(256), 0, stream,
                       w_qkv, w_out, wq_eff, wo_eff);
    hipLaunchKernelGGL(qkv_conv_kernel, dim3(12, 36, 2), dim3(256), 0, stream,
                       x, wq_eff, qkvb);
    hipLaunchKernelGGL(dnorm_bf16_kernel, dim3(16, 9), dim3(256), 0, stream,
                       qkvb, qn, kn, vn);
    hipLaunchKernelGGL(attn_mfma_kernel, dim3(36, 16), dim3(256), 0, stream,
                       qn, kn, vn, y2);
    hipLaunchKernelGGL(out_conv_kernel, dim3(4, 36, 2), dim3(256), 0, stream,
                       y2, wo_eff, x, out);
}

// Round 3
// 143.961 us; speedup vs baseline: 3.3037x; 1.2090x over previous
//
#include <hip/hip_runtime.h>
#include <math.h>

#define EPSN 1e-4f
#define SEQ 2304

using bf16x8 = __attribute__((ext_vector_type(8))) short;
using f32x4  = __attribute__((ext_vector_type(4))) float;

__device__ inline unsigned short f2bf(float x) {
    union { float f; unsigned u; } c; c.f = x;
    unsigned u = c.u;
    u += 0x7fffu + ((u >> 16) & 1u);
    return (unsigned short)(u >> 16);
}
__device__ inline float bf2f(unsigned short b) {
    union { unsigned u; float f; } c; c.u = ((unsigned)b) << 16;
    return c.f;
}

// ---------------- Kernel 1: weight normalization -> bf16 ----------------
// w_eff[o,i] = w[o,i] / (16*EPS + ||w[o]||)
__global__ __launch_bounds__(256) void wnorm_kernel(const float* __restrict__ w_qkv,
                                                    const float* __restrict__ w_out,
                                                    unsigned short* __restrict__ wqb,
                                                    unsigned short* __restrict__ wob) {
    int row = blockIdx.x;
    const float* src;
    unsigned short* dst;
    if (row < 768) { src = w_qkv + row * 256; dst = wqb + row * 256; }
    else           { src = w_out + (row - 768) * 256; dst = wob + (row - 768) * 256; }
    float v = src[threadIdx.x];
    float ss = v * v;
    for (int off = 32; off > 0; off >>= 1) ss += __shfl_down(ss, off, 64);
    __shared__ float red[4];
    __shared__ float scale_s;
    int lane = threadIdx.x & 63, wid = threadIdx.x >> 6;
    if (lane == 0) red[wid] = ss;
    __syncthreads();
    if (threadIdx.x == 0) {
        float t = red[0] + red[1] + red[2] + red[3];
        scale_s = 1.0f / (sqrtf(t) + 16.0f * EPSN);
    }
    __syncthreads();
    dst[threadIdx.x] = f2bf(v * scale_s);
}

// ---------------- Kernel 2: transpose x -> xt[n][s][c] bf16 ----------------
__global__ __launch_bounds__(256) void xt_kernel(const float* __restrict__ x,
                                                 unsigned short* __restrict__ xt) {
    __shared__ __align__(16) unsigned short T[64][80];
    int st = blockIdx.x;   // 0..35 (64 s each)
    int ct = blockIdx.y;   // 0..3  (64 c each)
    int n  = blockIdx.z;
    int t = threadIdx.x;
#pragma unroll
    for (int p = 0; p < 4; ++p) {
        int e = t + p * 256;
        int c = e >> 4, sv = (e & 15) * 4;
        float4 v = *(const float4*)&x[(size_t)(n * 256 + ct * 64 + c) * SEQ + st * 64 + sv];
        T[sv + 0][c] = f2bf(v.x);
        T[sv + 1][c] = f2bf(v.y);
        T[sv + 2][c] = f2bf(v.z);
        T[sv + 3][c] = f2bf(v.w);
    }
    __syncthreads();
#pragma unroll
    for (int p = 0; p < 2; ++p) {
        int e = t + p * 256;
        int s = e >> 3, cb = (e & 7) * 8;
        uint4 v = *(const uint4*)&T[s][cb];
        *(uint4*)&xt[(size_t)(n * SEQ + st * 64 + s) * 256 + ct * 64 + cb] = v;
    }
}

// ---------------- Kernel 3: QKV GEMM (bf16 MFMA, LDS-free) ----------------
// C[o][s] = W[o][k] X[k][s];  A = wqb[o][k] row-major, B = xt[s][k] row-major.
__global__ __launch_bounds__(256) void qkv_gemm_kernel(const unsigned short* __restrict__ xt,
                                                       const unsigned short* __restrict__ wqb,
                                                       unsigned short* __restrict__ qkvb) {
    int mt = blockIdx.x;   // 0..11
    int st = blockIdx.y;   // 0..35
    int n  = blockIdx.z;
    int tid = threadIdx.x;
    int wave = tid >> 6, lane = tid & 63;
    int ln = lane & 15, quad = lane >> 4;
    int m0 = mt * 64 + wave * 16;
    const unsigned short* Abase = wqb + (size_t)(m0 + ln) * 256 + quad * 8;
    const unsigned short* Bbase = xt + (size_t)(n * SEQ + st * 64 + ln) * 256 + quad * 8;
    f32x4 acc[4] = {{0.f,0.f,0.f,0.f},{0.f,0.f,0.f,0.f},{0.f,0.f,0.f,0.f},{0.f,0.f,0.f,0.f}};
#pragma unroll
    for (int kc = 0; kc < 8; ++kc) {
        bf16x8 a = *(const bf16x8*)(Abase + kc * 32);
#pragma unroll
        for (int c = 0; c < 4; ++c) {
            bf16x8 b = *(const bf16x8*)(Bbase + (size_t)(c * 16) * 256 + kc * 32);
            acc[c] = __builtin_amdgcn_mfma_f32_16x16x32_bf16(a, b, acc[c], 0, 0, 0);
        }
    }
#pragma unroll
    for (int c = 0; c < 4; ++c)
#pragma unroll
        for (int r = 0; r < 4; ++r) {
            int o = m0 + quad * 4 + r;
            int h = o / 96, rr = o % 96;
            int d = rr / 3, wh = rr % 3;
            int s = st * 64 + c * 16 + ln;
            qkvb[((size_t)((n * 8 + h) * 3 + wh) * 32 + d) * SEQ + s] = f2bf(acc[c][r]);
        }
}

// ---------------- Kernel 4: d-normalize, emit MFMA-friendly bf16 layouts ----------------
// qn, kn: [nh][s][d];  vn: [nh][d][s].  Q gets 1/sqrt(32) folded in.
__global__ __launch_bounds__(256) void dnorm_bf16_kernel(const unsigned short* __restrict__ qkvb,
                                                         unsigned short* __restrict__ qn,
                                                         unsigned short* __restrict__ kn,
                                                         unsigned short* __restrict__ vn) {
    int nh = blockIdx.x;                      // 0..15
    int s = blockIdx.y * 256 + threadIdx.x;   // 0..2303
    const float qscale = 0.17677669529663687f;
#pragma unroll
    for (int which = 0; which < 3; ++which) {
        const unsigned short* base = qkvb + ((size_t)(nh * 3 + which) * 32) * SEQ + s;
        float v[32];
        float ss = 0.f;
#pragma unroll
        for (int d = 0; d < 32; ++d) { v[d] = bf2f(base[(size_t)d * SEQ]); ss += v[d] * v[d]; }
        float inv = 1.0f / (EPSN + sqrtf(ss * (1.0f / 32.0f)));
        if (which == 0) inv *= qscale;
        if (which == 2) {
            unsigned short* dst = vn + (size_t)nh * 73728 + s;
#pragma unroll
            for (int d = 0; d < 32; ++d) dst[(size_t)d * SEQ] = f2bf(v[d] * inv);
        } else {
            unsigned short* dst = (which ? kn : qn) + (size_t)nh * 73728 + (size_t)s * 32;
            unsigned wbuf[16];
#pragma unroll
            for (int j = 0; j < 16; ++j)
                wbuf[j] = (unsigned)f2bf(v[2 * j] * inv) | ((unsigned)f2bf(v[2 * j + 1] * inv) << 16);
#pragma unroll
            for (int j = 0; j < 4; ++j) {
                uint4 t = make_uint4(wbuf[4 * j], wbuf[4 * j + 1], wbuf[4 * j + 2], wbuf[4 * j + 3]);
                *(uint4*)(dst + j * 8) = t;
            }
        }
    }
}

// ---------------- Kernel 5: MFMA flash attention, split-K=2 ----------------
// grid (36 q-tiles, 16 nh, 2 kz); partial O (unnormalized) + l to ws.
__global__ __launch_bounds__(256) void attn_mfma_kernel(const unsigned short* __restrict__ qn,
                                                        const unsigned short* __restrict__ kn,
                                                        const unsigned short* __restrict__ vn,
                                                        float* __restrict__ Opart,
                                                        float* __restrict__ Lpart) {
    __shared__ __align__(16) unsigned short Ks[64][40];
    __shared__ __align__(16) unsigned short Vs[32][72];
    __shared__ __align__(16) unsigned short Ps[4][16][72];
    int tid = threadIdx.x;
    int wave = tid >> 6, lane = tid & 63;
    int ln = lane & 15, quad = lane >> 4;
    int qt = blockIdx.x, nh = blockIdx.y, kz = blockIdx.z;
    const unsigned short* Qg = qn + (size_t)nh * 73728;
    const unsigned short* Kg = kn + (size_t)nh * 73728;
    const unsigned short* Vg = vn + (size_t)nh * 73728;

    bf16x8 qf = *(const bf16x8*)(Qg + (size_t)(qt * 64 + wave * 16 + ln) * 32 + quad * 8);
    bf16x8 ones;
#pragma unroll
    for (int i = 0; i < 8; ++i) ones[i] = (short)0x3F80;

    f32x4 o0 = {0.f, 0.f, 0.f, 0.f};
    f32x4 o1 = {0.f, 0.f, 0.f, 0.f};
    f32x4 lac = {0.f, 0.f, 0.f, 0.f};

    for (int kt = kz * 18; kt < kz * 18 + 18; ++kt) {
        int k0 = kt * 64;
        __syncthreads();
        {
            uint4 t = *(const uint4*)(Kg + (size_t)k0 * 32 + tid * 8);
            *(uint4*)(&Ks[tid >> 2][(tid & 3) * 8]) = t;
        }
        {
            uint4 t = *(const uint4*)(Vg + (size_t)(tid >> 3) * SEQ + k0 + (tid & 7) * 8);
            *(uint4*)(&Vs[tid >> 3][(tid & 7) * 8]) = t;
        }
        __syncthreads();

        const f32x4 zero = {0.f, 0.f, 0.f, 0.f};
#pragma unroll
        for (int c = 0; c < 4; ++c) {
            bf16x8 kf = *(const bf16x8*)(&Ks[c * 16 + ln][quad * 8]);
            f32x4 sc = __builtin_amdgcn_mfma_f32_16x16x32_bf16(qf, kf, zero, 0, 0, 0);
#pragma unroll
            for (int r = 0; r < 4; ++r)
                Ps[wave][quad * 4 + r][c * 16 + ln] = f2bf(__expf(sc[r]));
        }
        __syncthreads();

#pragma unroll
        for (int kc = 0; kc < 2; ++kc) {
            bf16x8 pf = *(const bf16x8*)(&Ps[wave][ln][kc * 32 + quad * 8]);
            bf16x8 v0 = *(const bf16x8*)(&Vs[ln][kc * 32 + quad * 8]);
            bf16x8 v1 = *(const bf16x8*)(&Vs[16 + ln][kc * 32 + quad * 8]);
            lac = __builtin_amdgcn_mfma_f32_16x16x32_bf16(pf, ones, lac, 0, 0, 0);
            o0  = __builtin_amdgcn_mfma_f32_16x16x32_bf16(pf, v0, o0, 0, 0, 0);
            o1  = __builtin_amdgcn_mfma_f32_16x16x32_bf16(pf, v1, o1, 0, 0, 0);
        }
    }

    float* Ob = Opart + ((size_t)(kz * 16 + nh) * 36 + qt) * 2048;
    float* Lb = Lpart + ((size_t)(kz * 16 + nh) * 36 + qt) * 64;
#pragma unroll
    for (int r = 0; r < 4; ++r) {
        int ql = wave * 16 + quad * 4 + r;
        Ob[ql * 32 + ln]      = o0[r];
        Ob[ql * 32 + 16 + ln] = o1[r];
        if (ln == 0) Lb[ql] = lac[r];
    }
}

// ---------------- Kernel 6: split-K reduce -> y2t[n][s][c] bf16 ----------------
__global__ __launch_bounds__(256) void attn_reduce_kernel(const float* __restrict__ Opart,
                                                          const float* __restrict__ Lpart,
                                                          unsigned short* __restrict__ y2t) {
    int qt = blockIdx.x, nh = blockIdx.y;
    int n = nh >> 3, h = nh & 7;
    const float* O0 = Opart + ((size_t)nh * 36 + qt) * 2048;
    const float* O1 = Opart + ((size_t)(16 + nh) * 36 + qt) * 2048;
    const float* L0 = Lpart + ((size_t)nh * 36 + qt) * 64;
    const float* L1 = Lpart + ((size_t)(16 + nh) * 36 + qt) * 64;
#pragma unroll
    for (int p = 0; p < 8; ++p) {
        int idx = threadIdx.x + p * 256;
        int q = idx >> 5, c = idx & 31;
        float l = L0[q] + L1[q];
        float v = (O0[idx] + O1[idx]) / l;
        y2t[((size_t)(n * SEQ) + qt * 64 + q) * 256 + h * 32 + c] = f2bf(v);
    }
}

// ---------------- Kernel 7: out GEMM (bf16 MFMA, LDS-free) + residual ----------------
__global__ __launch_bounds__(256) void out_gemm_kernel(const unsigned short* __restrict__ y2t,
                                                       const unsigned short* __restrict__ wob,
                                                       const float* __restrict__ x,
                                                       float* __restrict__ out) {
    int mt = blockIdx.x;   // 0..3
    int st = blockIdx.y;   // 0..35
    int n  = blockIdx.z;
    int tid = threadIdx.x;
    int wave = tid >> 6, lane = tid & 63;
    int ln = lane & 15, quad = lane >> 4;
    int m0 = mt * 64 + wave * 16;
    const unsigned short* Abase = wob + (size_t)(m0 + ln) * 256 + quad * 8;
    const unsigned short* Bbase = y2t + (size_t)(n * SEQ + st * 64 + ln) * 256 + quad * 8;
    f32x4 acc[4] = {{0.f,0.f,0.f,0.f},{0.f,0.f,0.f,0.f},{0.f,0.f,0.f,0.f},{0.f,0.f,0.f,0.f}};
#pragma unroll
    for (int kc = 0; kc < 8; ++kc) {
        bf16x8 a = *(const bf16x8*)(Abase + kc * 32);
#pragma unroll
        for (int c = 0; c < 4; ++c) {
            bf16x8 b = *(const bf16x8*)(Bbase + (size_t)(c * 16) * 256 + kc * 32);
            acc[c] = __builtin_amdgcn_mfma_f32_16x16x32_bf16(a, b, acc[c], 0, 0, 0);
        }
    }
    const float c0f = 0.7f * 1.3130643285972254f;
    const float c1f = 0.3f * 1.3130643285972254f;
#pragma unroll
    for (int c = 0; c < 4; ++c)
#pragma unroll
        for (int r = 0; r < 4; ++r) {
            int o = m0 + quad * 4 + r;
            int s = st * 64 + c * 16 + ln;
            size_t idx = (size_t)(n * 256 + o) * SEQ + s;
            out[idx] = c0f * x[idx] + c1f * acc[c][r];
        }
}

extern "C" void kernel_launch(void* const* d_in, const int* in_sizes, int n_in,
                              void* d_out, int out_size, void* d_ws, size_t ws_size,
                              hipStream_t stream) {
    (void)in_sizes; (void)n_in; (void)out_size; (void)ws_size;
    const float* x     = (const float*)d_in[0];
    const float* w_qkv = (const float*)d_in[1];
    const float* w_out = (const float*)d_in[2];
    float* out = (float*)d_out;
    float* ws  = (float*)d_ws;
    // Region A (f-offsets) -- dead after dnorm, aliased by attention partials:
    unsigned short* xt   = (unsigned short*)(ws);            // [0, 589824) f
    unsigned short* wqb  = (unsigned short*)(ws + 589824);   // [589824, 688128) f
    unsigned short* qkvb = (unsigned short*)(ws + 688128);   // [688128, 2457600) f
    float* Opart = ws;                                       // [0, 2359296) f  (alias)
    float* Lpart = ws + 2359296;                             // [2359296, 2433024) f (alias)
    // Region B:
    unsigned short* wob = (unsigned short*)(ws + 2457600);   // 65536 shorts
    unsigned short* qn  = (unsigned short*)(ws + 2490368);
    unsigned short* kn  = (unsigned short*)(ws + 3080192);
    unsigned short* vn  = (unsigned short*)(ws + 3670016);
    unsigned short* y2t = (unsigned short*)(ws + 4259840);   // ends 4849664 f = 19.4 MB

    hipLaunchKernelGGL(wnorm_kernel, dim3(1024), dim3(256), 0, stream,
                       w_qkv, w_out, wqb, wob);
    hipLaunchKernelGGL(xt_kernel, dim3(36, 4, 2), dim3(256), 0, stream, x, xt);
    hipLaunchKernelGGL(qkv_gemm_kernel, dim3(12, 36, 2), dim3(256), 0, stream,
                       xt, wqb, qkvb);
    hipLaunchKernelGGL(dnorm_bf16_kernel, dim3(16, 9), dim3(256), 0, stream,
                       qkvb, qn, kn, vn);
    hipLaunchKernelGGL(attn_mfma_kernel, dim3(36, 16, 2), dim3(256), 0, stream,
                       qn, kn, vn, Opart, Lpart);
    hipLaunchKernelGGL(attn_reduce_kernel, dim3(36, 16), dim3(256), 0, stream,
                       Opart, Lpart, y2t);
    hipLaunchKernelGGL(out_gemm_kernel, dim3(4, 36, 2), dim3(256), 0, stream,
                       y2t, wob, x, out);
}